// Round 1
// baseline (5440.737 us; speedup 1.0000x reference)
//
#include <hip/hip_runtime.h>
#include <hip/hip_bf16.h>

#define UDIM    256
#define ODIM    128
#define ZDIM    1024
#define NSTEPS  48
#define BM      32
#define THREADS 512
#define NBLOCKS 256   // (4096/32 row-groups) x 2 unit-halves

// ws layout (bytes):
//   [0, 786432)          KR fragments (ushort), 64 tiles x 12 kc x 64 lanes x 8
//   [786432, 851968)     D fragments (ushort),   8 tiles x  8 kc x 64 lanes x 8
//   [851968, 852992)     flags: 256 x u32 (zeroed by prep each launch)
//   [852992, 9241600)    h-exchange: 128 pairs x 2 halves x 2 parity x 4096 u32
#define KR_FRAGS 393216
#define D_FRAGS  32768
#define FLAG_BYTE_OFF 851968
#define XH_BYTE_OFF   852992

#define SA_W 396   // stride 792B = 198 dwords; 198%32=6 -> 16 distinct banks across rows

typedef short bf16x8 __attribute__((ext_vector_type(8)));
typedef float f32x4  __attribute__((ext_vector_type(4)));

__device__ __forceinline__ ushort f2bf_bits(float v) {
    __hip_bfloat16 b = __float2bfloat16(v);
    return *reinterpret_cast<ushort*>(&b);
}
__device__ __forceinline__ float bfbits2f(ushort u) {
    __hip_bfloat16 b = *reinterpret_cast<__hip_bfloat16*>(&u);
    return __bfloat162float(b);
}
__device__ __forceinline__ float sigmoid_f(float x) {
    return 1.0f / (1.0f + __expf(-x));
}
__device__ __forceinline__ float tanh_f(float x) {
    return 1.0f - 2.0f / (__expf(2.0f * x) + 1.0f);
}

// ---- prep: pack weights into MFMA B-fragment order (bf16 RNE), zero flags ----
__global__ void prep_weights(const float* __restrict__ kernel_w,   // [128,1024]
                             const float* __restrict__ rec_w,      // [256,1024]
                             const float* __restrict__ dense_w,    // [256,128]
                             ushort* __restrict__ ws) {
    int idx = blockIdx.x * blockDim.x + threadIdx.x;
    if (idx < KR_FRAGS) {
        int j  = idx & 7;
        int l  = (idx >> 3) & 63;
        int fc = idx >> 9;          // n*12 + kc
        int kc = fc % 12;
        int n  = fc / 12;
        int k   = kc * 32 + (l >> 4) * 8 + j;
        int col = n * 16 + (l & 15);
        float wv = (k < 128) ? kernel_w[k * ZDIM + col]
                             : rec_w[(k - 128) * ZDIM + col];
        ws[idx] = f2bf_bits(wv);
    } else if (idx < KR_FRAGS + D_FRAGS) {
        int e  = idx - KR_FRAGS;
        int j  = e & 7;
        int l  = (e >> 3) & 63;
        int kc = (e >> 9) & 7;
        int n  = e >> 12;
        int k   = kc * 32 + (l >> 4) * 8 + j;
        int col = n * 16 + (l & 15);
        ws[KR_FRAGS + e] = f2bf_bits(dense_w[k * ODIM + col]);
    } else if (idx < KR_FRAGS + D_FRAGS + 256) {
        uint* flags = (uint*)((char*)ws + FLAG_BYTE_OFF);
        flags[idx - KR_FRAGS - D_FRAGS] = 0u;
    }
}

// ---- main: pair-split persistent LSTM. Each block: 32 rows x 128 units. ----
// Pair = blocks (bid, bid^8)  [same XCD under round-robin mapping — perf only].
// Wave w=jg (0..7) owns unit-group jg: all 4 gates x both row-tiles,
// so each B-fragment is loaded exactly once per block and reused for 4 MFMAs.
__global__ __launch_bounds__(THREADS, 4) void lstm_mfma_kernel(
    const float* __restrict__ last_input,  // [4096,128]
    const float* __restrict__ h0,          // [4096,256]
    const float* __restrict__ c0,          // [4096,256]
    const float* __restrict__ bias,        // [1024]
    const float* __restrict__ dense_b,     // [128]
    ushort* __restrict__ ws,
    float* __restrict__ out)               // [4096,48,128]
{
    const ushort* KR = ws;
    const ushort* Dw = ws + KR_FRAGS;
    uint* flags = (uint*)((char*)ws + FLAG_BYTE_OFF);
    uint* xh    = (uint*)((char*)ws + XH_BYTE_OFF);

    __shared__ ushort sA_hi[BM][SA_W];
    __shared__ ushort sA_lo[BM][SA_W];

    const int t  = threadIdx.x;
    const int w  = t >> 6;          // wave = unit-group jg, 0..7
    const int l  = t & 63;
    const int cl = l & 15;          // tile col / A row within tile
    const int rg = l >> 4;          // k-group / C row group

    const int bid      = blockIdx.x;
    const int hb       = (bid >> 3) & 1;                 // unit half 0/1
    const int pairIdx  = ((bid & 7) << 4) | (bid >> 4);  // 0..127, shared with partner (bid^8)
    const int fid      = pairIdx * 2 + hb;
    const int blockRow = pairIdx * BM;
    const int u0       = hb * 128;

    // ---- stage x0 (cols 0..127) and FULL h0 (cols 128..383), hi/lo split ----
    for (int i = t; i < BM * ODIM; i += THREADS) {
        int r = i >> 7, c = i & 127;
        float v = last_input[(blockRow + r) * ODIM + c];
        ushort hi = f2bf_bits(v);
        sA_hi[r][c] = hi;
        sA_lo[r][c] = f2bf_bits(v - bfbits2f(hi));
    }
    for (int i = t; i < BM * UDIM; i += THREADS) {
        int r = i >> 8, c = i & 255;
        float v = h0[(blockRow + r) * UDIM + c];
        ushort hi = f2bf_bits(v);
        sA_hi[r][128 + c] = hi;
        sA_lo[r][128 + c] = f2bf_bits(v - bfbits2f(hi));
    }

    const int unit_l = w * 16 + cl;     // local unit col 0..127 (also y col)
    const int unit   = u0 + unit_l;     // global unit 0..255

    // per-lane state: rows rt*16 + 4*rg + r, unit column `unit`
    float cstate[2][4];
    #pragma unroll
    for (int rt = 0; rt < 2; ++rt)
        #pragma unroll
        for (int r = 0; r < 4; ++r)
            cstate[rt][r] = c0[(blockRow + rt * 16 + 4 * rg + r) * UDIM + unit];

    int ng[4]; float bz[4];
    #pragma unroll
    for (int g = 0; g < 4; ++g) {
        ng[g] = g * 16 + hb * 8 + w;            // global n-tile of gate g
        bz[g] = bias[ng[g] * 16 + cl];          // = bias[g*256 + unit]
    }
    const float db = dense_b[unit_l];

    const ushort* bp[4];
    #pragma unroll
    for (int g = 0; g < 4; ++g) bp[g] = KR + (size_t)ng[g] * 6144 + l * 8;
    const ushort* dbase = Dw + (size_t)w * 4096 + l * 8;

    uint* xo_base = xh + (size_t)fid * 2 * 4096;
    uint* xi_base = xh + (size_t)(fid ^ 1) * 2 * 4096;

    __syncthreads();

    for (int s = 0; s < NSTEPS; ++s) {
        // ======== GEMM1: Z[32, own 512 cols] = A[32,384] @ KR + bias (hi/lo 2-pass) ========
        f32x4 acc[4][2];
        #pragma unroll
        for (int g = 0; g < 4; ++g) {
            acc[g][0] = (f32x4){bz[g], bz[g], bz[g], bz[g]};
            acc[g][1] = (f32x4){bz[g], bz[g], bz[g], bz[g]};
        }

        bf16x8 bcur[4];
        #pragma unroll
        for (int g = 0; g < 4; ++g) bcur[g] = *reinterpret_cast<const bf16x8*>(bp[g]);

        #pragma unroll
        for (int kc = 0; kc < 12; ++kc) {
            bf16x8 bnxt[4];
            if (kc < 11) {
                #pragma unroll
                for (int g = 0; g < 4; ++g)
                    bnxt[g] = *reinterpret_cast<const bf16x8*>(bp[g] + (kc + 1) * 512);
            }
            const int koff = kc * 32 + rg * 8;
            bf16x8 a0h = *reinterpret_cast<const bf16x8*>(&sA_hi[cl][koff]);
            bf16x8 a0l = *reinterpret_cast<const bf16x8*>(&sA_lo[cl][koff]);
            bf16x8 a1h = *reinterpret_cast<const bf16x8*>(&sA_hi[16 + cl][koff]);
            bf16x8 a1l = *reinterpret_cast<const bf16x8*>(&sA_lo[16 + cl][koff]);
            #pragma unroll
            for (int g = 0; g < 4; ++g) {
                acc[g][0] = __builtin_amdgcn_mfma_f32_16x16x32_bf16(a0h, bcur[g], acc[g][0], 0, 0, 0);
                acc[g][0] = __builtin_amdgcn_mfma_f32_16x16x32_bf16(a0l, bcur[g], acc[g][0], 0, 0, 0);
                acc[g][1] = __builtin_amdgcn_mfma_f32_16x16x32_bf16(a1h, bcur[g], acc[g][1], 0, 0, 0);
                acc[g][1] = __builtin_amdgcn_mfma_f32_16x16x32_bf16(a1l, bcur[g], acc[g][1], 0, 0, 0);
            }
            #pragma unroll
            for (int g = 0; g < 4; ++g) bcur[g] = bnxt[g];
        }

        // ======== gates + state update (registers; all 4 gates are wave-local) ========
        ushort hhi[2][4], hlo[2][4]; uint hpk[2][4];
        #pragma unroll
        for (int rt = 0; rt < 2; ++rt) {
            #pragma unroll
            for (int r = 0; r < 4; ++r) {
                float iv = sigmoid_f(acc[0][rt][r]);
                float fv = sigmoid_f(acc[1][rt][r]);
                float gv = tanh_f(acc[2][rt][r]);
                float ov = sigmoid_f(acc[3][rt][r]);
                float cn = fv * cstate[rt][r] + iv * gv;
                cstate[rt][r] = cn;
                float hv = ov * tanh_f(cn);
                ushort hi = f2bf_bits(hv);
                ushort lo = f2bf_bits(hv - bfbits2f(hi));
                hhi[rt][r] = hi; hlo[rt][r] = lo;
                hpk[rt][r] = (uint)hi | ((uint)lo << 16);
            }
        }
        // publish own h-half to partner (global, device-coherent; doesn't touch LDS)
        uint* xo = xo_base + (s & 1) * 4096;
        #pragma unroll
        for (int rt = 0; rt < 2; ++rt)
            #pragma unroll
            for (int r = 0; r < 4; ++r)
                __hip_atomic_store(&xo[(rt * 16 + 4 * rg + r) * 128 + unit_l], hpk[rt][r],
                                   __ATOMIC_RELAXED, __HIP_MEMORY_SCOPE_AGENT);

        __syncthreads();   // B1: all GEMM1 reads of sA complete

        // own h-half into sA
        #pragma unroll
        for (int rt = 0; rt < 2; ++rt)
            #pragma unroll
            for (int r = 0; r < 4; ++r) {
                int row = rt * 16 + 4 * rg + r;
                sA_hi[row][128 + unit] = hhi[rt][r];
                sA_lo[row][128 + unit] = hlo[rt][r];
            }
        __threadfence();   // drain exchange stores (device scope)
        __syncthreads();   // B2: own h in sA; all lanes' exchange stores fenced
        if (t == 0)
            __hip_atomic_store(&flags[fid], (uint)(s + 1),
                               __ATOMIC_RELEASE, __HIP_MEMORY_SCOPE_AGENT);

        // ======== dense, own-half K first (overlaps partner latency) ========
        f32x4 dacc[2];
        dacc[0] = (f32x4){db, db, db, db};
        dacc[1] = (f32x4){db, db, db, db};
        #pragma unroll
        for (int kk = 0; kk < 4; ++kk) {
            const int kc = hb * 4 + kk;
            const int koff = 128 + kc * 32 + rg * 8;
            bf16x8 b = *reinterpret_cast<const bf16x8*>(dbase + kc * 512);
            #pragma unroll
            for (int rt = 0; rt < 2; ++rt) {
                bf16x8 ah = *reinterpret_cast<const bf16x8*>(&sA_hi[rt * 16 + cl][koff]);
                bf16x8 al = *reinterpret_cast<const bf16x8*>(&sA_lo[rt * 16 + cl][koff]);
                dacc[rt] = __builtin_amdgcn_mfma_f32_16x16x32_bf16(ah, b, dacc[rt], 0, 0, 0);
                dacc[rt] = __builtin_amdgcn_mfma_f32_16x16x32_bf16(al, b, dacc[rt], 0, 0, 0);
            }
        }

        // ======== wait for partner h-half, land it in sA ========
        {
            const uint tgt = (uint)(s + 1);
            while (__hip_atomic_load(&flags[fid ^ 1], __ATOMIC_RELAXED,
                                     __HIP_MEMORY_SCOPE_AGENT) < tgt) { }
        }
        __threadfence();
        const uint* xi = xi_base + (s & 1) * 4096;
        #pragma unroll
        for (int k = 0; k < 8; ++k) {
            int e = t + k * THREADS;
            uint v = __hip_atomic_load(&xi[e], __ATOMIC_RELAXED, __HIP_MEMORY_SCOPE_AGENT);
            int row = e >> 7, lu = e & 127;
            sA_hi[row][128 + (u0 ^ 128) + lu] = (ushort)(v & 0xffffu);
            sA_lo[row][128 + (u0 ^ 128) + lu] = (ushort)(v >> 16);
        }
        __syncthreads();   // B3: full h in sA

        // ======== dense, partner-half K ========
        #pragma unroll
        for (int kk = 0; kk < 4; ++kk) {
            const int kc = (hb ^ 1) * 4 + kk;
            const int koff = 128 + kc * 32 + rg * 8;
            bf16x8 b = *reinterpret_cast<const bf16x8*>(dbase + kc * 512);
            #pragma unroll
            for (int rt = 0; rt < 2; ++rt) {
                bf16x8 ah = *reinterpret_cast<const bf16x8*>(&sA_hi[rt * 16 + cl][koff]);
                bf16x8 al = *reinterpret_cast<const bf16x8*>(&sA_lo[rt * 16 + cl][koff]);
                dacc[rt] = __builtin_amdgcn_mfma_f32_16x16x32_bf16(ah, b, dacc[rt], 0, 0, 0);
                dacc[rt] = __builtin_amdgcn_mfma_f32_16x16x32_bf16(al, b, dacc[rt], 0, 0, 0);
            }
        }

        // ======== y = relu(...): store own cols to out, feed back as next x ========
        #pragma unroll
        for (int rt = 0; rt < 2; ++rt) {
            #pragma unroll
            for (int r = 0; r < 4; ++r) {
                float y = fmaxf(dacc[rt][r], 0.0f);
                int row = rt * 16 + 4 * rg + r;
                if ((w >> 2) == hb)
                    out[((size_t)(blockRow + row) * NSTEPS + s) * ODIM + unit_l] = y;
                ushort yb = f2bf_bits(y);
                sA_hi[row][unit_l] = yb;
                sA_lo[row][unit_l] = f2bf_bits(y - bfbits2f(yb));
            }
        }
        __syncthreads();   // B4: next-step x ready
    }
}

extern "C" void kernel_launch(void* const* d_in, const int* in_sizes, int n_in,
                              void* d_out, int out_size, void* d_ws, size_t ws_size,
                              hipStream_t stream) {
    const float* last_input = (const float*)d_in[0];
    const float* h0         = (const float*)d_in[1];
    const float* c0         = (const float*)d_in[2];
    const float* kernel_w   = (const float*)d_in[3];
    const float* rec_w      = (const float*)d_in[4];
    const float* bias       = (const float*)d_in[5];
    const float* dense_w    = (const float*)d_in[6];
    const float* dense_b    = (const float*)d_in[7];
    float* out  = (float*)d_out;
    ushort* ws  = (ushort*)d_ws;

    const int prep_total = KR_FRAGS + D_FRAGS + 256;
    hipLaunchKernelGGL(prep_weights, dim3((prep_total + 255) / 256), dim3(256), 0, stream,
                       kernel_w, rec_w, dense_w, ws);
    hipLaunchKernelGGL(lstm_mfma_kernel, dim3(NBLOCKS), dim3(THREADS), 0, stream,
                       last_input, h0, c0, bias, dense_b, ws, out);
}

// Round 2
// 567.016 us; speedup vs baseline: 9.5954x; 9.5954x over previous
//
#include <hip/hip_runtime.h>
#include <hip/hip_bf16.h>

#define UDIM    256
#define ODIM    128
#define ZDIM    1024
#define NSTEPS  48
#define BM      16
#define THREADS 1024
#define NBLOCKS 256   // 4096 / BM

// ws layout in ushort elements (weights rounded-to-nearest bf16, hi only):
//   KR_hi: [0,       393216)   64 tiles x 12 kc x 64 lanes x 8
//   D_hi : [393216,  425984)   8 tiles x 8 kc x 64 lanes x 8
#define KR_FRAGS 393216
#define D_FRAGS  32768

// sA geometry: cols [0,128)=x, [128,384)=h buf0, [384,640)=h buf1, pad to 664.
// Stride 664 ushort = 332 dwords == 12 (mod 32): 64-lane ds_read_b128 windows
// 12*cl + 16*kc + 4*rg hit every bank exactly 8x -> zero excess conflicts.
// Row bytes 1328 % 16 == 0 -> b128 alignment preserved.
#define SA_W 664

typedef short bf16x8 __attribute__((ext_vector_type(8)));
typedef float f32x4  __attribute__((ext_vector_type(4)));

__device__ __forceinline__ ushort f2bf_bits(float v) {
    __hip_bfloat16 b = __float2bfloat16(v);
    return *reinterpret_cast<ushort*>(&b);
}
__device__ __forceinline__ float bfbits2f(ushort u) {
    __hip_bfloat16 b = *reinterpret_cast<__hip_bfloat16*>(&u);
    return __bfloat162float(b);
}
__device__ __forceinline__ float sigmoid_f(float x) {
    return 1.0f / (1.0f + __expf(-x));
}
__device__ __forceinline__ float tanh_f(float x) {
    return 1.0f - 2.0f / (__expf(2.0f * x) + 1.0f);
}

// ---- prep: pack weights into MFMA B-fragment order, bf16 (round-nearest) ----
__global__ void prep_weights(const float* __restrict__ kernel_w,   // [128,1024]
                             const float* __restrict__ rec_w,      // [256,1024]
                             const float* __restrict__ dense_w,    // [256,128]
                             ushort* __restrict__ ws) {
    int idx = blockIdx.x * blockDim.x + threadIdx.x;
    if (idx < KR_FRAGS) {
        int j  = idx & 7;
        int l  = (idx >> 3) & 63;
        int fc = idx >> 9;          // n*12 + kc
        int kc = fc % 12;
        int n  = fc / 12;
        int k   = kc * 32 + (l >> 4) * 8 + j;
        int col = n * 16 + (l & 15);
        float wv = (k < 128) ? kernel_w[k * ZDIM + col]
                             : rec_w[(k - 128) * ZDIM + col];
        ws[idx] = f2bf_bits(wv);
    } else if (idx < KR_FRAGS + D_FRAGS) {
        int e  = idx - KR_FRAGS;
        int j  = e & 7;
        int l  = (e >> 3) & 63;
        int kc = (e >> 9) & 7;
        int n  = e >> 12;
        int k   = kc * 32 + (l >> 4) * 8 + j;
        int col = n * 16 + (l & 15);
        ws[KR_FRAGS + e] = f2bf_bits(dense_w[k * ODIM + col]);
    }
}

// ---- main: persistent per-block LSTM, 48 steps, 2-pass split-A MFMA ----
// vs round-0 baseline: conflict-free LDS stride, dense weights in LDS,
// kc{0,1} B-fragments register-cached, h double-buffered (2 barriers/step).
__global__ __launch_bounds__(THREADS, 4) void lstm_mfma_kernel(
    const float* __restrict__ last_input,  // [4096,128]
    const float* __restrict__ h0,          // [4096,256]
    const float* __restrict__ c0,          // [4096,256]
    const float* __restrict__ bias,        // [1024]
    const float* __restrict__ dense_b,     // [128]
    const ushort* __restrict__ wsro,
    float* __restrict__ out)               // [4096,48,128]
{
    const ushort* KR = wsro;

    __shared__ ushort sA_hi[BM][SA_W];
    __shared__ ushort sA_lo[BM][SA_W];
    __shared__ __align__(16) ushort sDw[D_FRAGS];

    const int t  = threadIdx.x;
    const int w  = t >> 6;          // wave 0..15
    const int l  = t & 63;
    const int cl = l & 15;          // tile col / A row
    const int rg = l >> 4;          // 0..3 -> C rows 4*rg..+4, k-group
    const int blockRow = blockIdx.x * BM;

    // ---- stage dense weights into LDS (once) ----
    for (int i = t * 8; i < D_FRAGS; i += THREADS * 8)
        *reinterpret_cast<bf16x8*>(&sDw[i]) =
            *reinterpret_cast<const bf16x8*>(&wsro[KR_FRAGS + i]);

    // ---- stage x0 (cols 0..127) and h0 (buf1: cols 384..639) ----
    for (int i = t; i < BM * ODIM; i += THREADS) {
        int r = i >> 7, c = i & 127;
        float v = last_input[(blockRow + r) * ODIM + c];
        ushort hi = f2bf_bits(v);
        sA_hi[r][c] = hi;
        sA_lo[r][c] = f2bf_bits(v - bfbits2f(hi));
    }
    for (int i = t; i < BM * UDIM; i += THREADS) {
        int r = i >> 8, c = i & 255;
        float v = h0[(blockRow + r) * UDIM + c];
        ushort hi = f2bf_bits(v);
        sA_hi[r][384 + c] = hi;
        sA_lo[r][384 + c] = f2bf_bits(v - bfbits2f(hi));
    }

    // ---- per-lane state: wave w owns units u = 16*w + cl, rows 4*rg..+4 ----
    const int unit = 16 * w + cl;
    float cstate[4];
    #pragma unroll
    for (int r = 0; r < 4; ++r)
        cstate[r] = c0[(blockRow + 4 * rg + r) * UDIM + unit];

    float bz[4];
    #pragma unroll
    for (int g = 0; g < 4; ++g)
        bz[g] = bias[256 * g + unit];
    const float db = dense_b[16 * (w & 7) + cl];

    // per-gate fragment base pointers (tile n = w + 16*g)
    const ushort* bp[4];
    #pragma unroll
    for (int g = 0; g < 4; ++g)
        bp[g] = KR + (size_t)(w + 16 * g) * 6144 + l * 8;

    // ---- register-cache kc 0,1 B-fragments (step-invariant) ----
    bf16x8 bc[2][4];
    #pragma unroll
    for (int kc = 0; kc < 2; ++kc)
        #pragma unroll
        for (int g = 0; g < 4; ++g)
            bc[kc][g] = *reinterpret_cast<const bf16x8*>(bp[g] + kc * 512);

    __syncthreads();

    for (int s = 0; s < NSTEPS; ++s) {
        const int pw  = s & 1;
        const int hrd = 128 + (pw ^ 1) * 256;   // h read base (prev step's buffer)
        const int hwr = 128 + pw * 256;         // h write base (this step's buffer)

        // ======== GEMM1: Z[16,1024] = A[16,384] @ KR + bias (hi/lo 2-pass) ========
        f32x4 acc[4];
        #pragma unroll
        for (int g = 0; g < 4; ++g)
            acc[g] = (f32x4){bz[g], bz[g], bz[g], bz[g]};

        // kc 0,1: register-cached B, x-region A (zero load-wait)
        #pragma unroll
        for (int kc = 0; kc < 2; ++kc) {
            const int koff = kc * 32 + rg * 8;
            bf16x8 a_hi = *reinterpret_cast<const bf16x8*>(&sA_hi[cl][koff]);
            bf16x8 a_lo = *reinterpret_cast<const bf16x8*>(&sA_lo[cl][koff]);
            #pragma unroll
            for (int g = 0; g < 4; ++g) {
                acc[g] = __builtin_amdgcn_mfma_f32_16x16x32_bf16(a_hi, bc[kc][g], acc[g], 0, 0, 0);
                acc[g] = __builtin_amdgcn_mfma_f32_16x16x32_bf16(a_lo, bc[kc][g], acc[g], 0, 0, 0);
            }
        }

        // kc 2..11: streamed B with 1-deep prefetch
        bf16x8 bcur[4];
        #pragma unroll
        for (int g = 0; g < 4; ++g)
            bcur[g] = *reinterpret_cast<const bf16x8*>(bp[g] + 2 * 512);

        #pragma unroll 5
        for (int kc = 2; kc < 12; ++kc) {
            bf16x8 bnxt[4];
            if (kc < 11) {
                #pragma unroll
                for (int g = 0; g < 4; ++g)
                    bnxt[g] = *reinterpret_cast<const bf16x8*>(bp[g] + (kc + 1) * 512);
            }
            const int koff = (kc < 4) ? (kc * 32 + rg * 8)
                                      : (hrd + (kc - 4) * 32 + rg * 8);
            bf16x8 a_hi = *reinterpret_cast<const bf16x8*>(&sA_hi[cl][koff]);
            bf16x8 a_lo = *reinterpret_cast<const bf16x8*>(&sA_lo[cl][koff]);
            #pragma unroll
            for (int g = 0; g < 4; ++g) {
                acc[g] = __builtin_amdgcn_mfma_f32_16x16x32_bf16(a_hi, bcur[g], acc[g], 0, 0, 0);
                acc[g] = __builtin_amdgcn_mfma_f32_16x16x32_bf16(a_lo, bcur[g], acc[g], 0, 0, 0);
            }
            #pragma unroll
            for (int g = 0; g < 4; ++g) bcur[g] = bnxt[g];
        }

        // ======== gates + state update; h_new straight into the OTHER buffer ========
        // Safe without a barrier: buffer hwr was last read in GEMM1(s-1); every
        // wave here has passed barrier B4(s-1), so no wave can still be there.
        #pragma unroll
        for (int r = 0; r < 4; ++r) {
            float iv = sigmoid_f(acc[0][r]);
            float fv = sigmoid_f(acc[1][r]);
            float gv = tanh_f(acc[2][r]);
            float ov = sigmoid_f(acc[3][r]);
            float cn = fv * cstate[r] + iv * gv;
            cstate[r] = cn;
            float hv = ov * tanh_f(cn);
            ushort hib = f2bf_bits(hv);
            int row = 4 * rg + r;
            sA_hi[row][hwr + unit] = hib;
            sA_lo[row][hwr + unit] = f2bf_bits(hv - bfbits2f(hib));
        }
        __syncthreads();   // B2: h_new visible (also fences GEMM1 reads vs y-write)

        // ======== dense: Y[16,128] = H[16,256] @ Wd + bd, relu (B from LDS) ========
        if (w < 8) {
            f32x4 dacc = (f32x4){db, db, db, db};
            #pragma unroll
            for (int kc = 0; kc < 8; ++kc) {
                const int koff = hwr + kc * 32 + rg * 8;
                bf16x8 a_hi = *reinterpret_cast<const bf16x8*>(&sA_hi[cl][koff]);
                bf16x8 a_lo = *reinterpret_cast<const bf16x8*>(&sA_lo[cl][koff]);
                bf16x8 b = *reinterpret_cast<const bf16x8*>(&sDw[w * 4096 + kc * 512 + l * 8]);
                dacc = __builtin_amdgcn_mfma_f32_16x16x32_bf16(a_hi, b, dacc, 0, 0, 0);
                dacc = __builtin_amdgcn_mfma_f32_16x16x32_bf16(a_lo, b, dacc, 0, 0, 0);
            }
            #pragma unroll
            for (int r = 0; r < 4; ++r) {
                float y = fmaxf(dacc[r], 0.0f);
                int row = 4 * rg + r;
                out[((size_t)(blockRow + row) * NSTEPS + s) * ODIM + 16 * w + cl] = y;
                ushort yb = f2bf_bits(y);
                sA_hi[row][16 * w + cl] = yb;
                sA_lo[row][16 * w + cl] = f2bf_bits(y - bfbits2f(yb));
            }
        }
        __syncthreads();   // B4: next-step x ready
    }
}

extern "C" void kernel_launch(void* const* d_in, const int* in_sizes, int n_in,
                              void* d_out, int out_size, void* d_ws, size_t ws_size,
                              hipStream_t stream) {
    const float* last_input = (const float*)d_in[0];
    const float* h0         = (const float*)d_in[1];
    const float* c0         = (const float*)d_in[2];
    const float* kernel_w   = (const float*)d_in[3];
    const float* rec_w      = (const float*)d_in[4];
    const float* bias       = (const float*)d_in[5];
    const float* dense_w    = (const float*)d_in[6];
    const float* dense_b    = (const float*)d_in[7];
    float* out  = (float*)d_out;
    ushort* ws  = (ushort*)d_ws;

    const int prep_total = KR_FRAGS + D_FRAGS;
    hipLaunchKernelGGL(prep_weights, dim3((prep_total + 255) / 256), dim3(256), 0, stream,
                       kernel_w, rec_w, dense_w, ws);
    hipLaunchKernelGGL(lstm_mfma_kernel, dim3(NBLOCKS), dim3(THREADS), 0, stream,
                       last_input, h0, c0, bias, dense_b, (const ushort*)ws, out);
}